// Round 1
// baseline (3608.809 us; speedup 1.0000x reference)
//
#include <hip/hip_runtime.h>
#include <hip/hip_fp16.h>
#include <stdint.h>

#define S_LEN 1024
#define BATCH 64
#define HID   512
#define VOC   256

typedef _Float16 h2v __attribute__((ext_vector_type(2)));
typedef _Float16 h8v __attribute__((ext_vector_type(8)));
typedef float    f4v __attribute__((ext_vector_type(4)));

__device__ __forceinline__ float fdot2f(uint32_t w, uint32_t h, float c) {
#if __has_builtin(__builtin_amdgcn_fdot2)
  return __builtin_amdgcn_fdot2(__builtin_bit_cast(h2v, w),
                                __builtin_bit_cast(h2v, h), c, false);
#else
  h2v a = __builtin_bit_cast(h2v, w);
  h2v b = __builtin_bit_cast(h2v, h);
  return c + (float)a.x * (float)b.x + (float)a.y * (float)b.y;
#endif
}

// ---------------- prep kernels ----------------
// Wp[k2*HID + n] = fp16 pair (W_hh[2*k2][n], W_hh[2*k2+1][n])
__global__ void prep_whh(const float* __restrict__ whh, uint32_t* __restrict__ wp) {
  int idx = blockIdx.x * blockDim.x + threadIdx.x;   // 131072 = 256*512
  int k2 = idx >> 9;
  int n  = idx & 511;
  float a = whh[(2 * k2) * HID + n];
  float b = whh[(2 * k2 + 1) * HID + n];
  h2v p;
  p.x = (_Float16)a;
  p.y = (_Float16)b;
  wp[idx] = __builtin_bit_cast(uint32_t, p);
}

// W_hyT[v*HID + k] = fp16 W_hy[k][v]   (n-major, k contiguous, for MFMA B frags)
__global__ void prep_why(const float* __restrict__ why, _Float16* __restrict__ wt) {
  int idx = blockIdx.x * blockDim.x + threadIdx.x;   // 131072 = 256*512
  int v = idx >> 9;
  int k = idx & 511;
  wt[idx] = (_Float16)why[k * VOC + v];
}

// ---------------- phase 1: recurrence ----------------
// 64 blocks (one per batch), 1024 threads.
// thread = (kq = tid>>7 in [0,8), nb = tid&127): owns cols n0=nb*4..+4, k-pairs [kq*32, kq*32+32)
__global__ __launch_bounds__(1024, 1) void rnn_phase1(
    const int* __restrict__ x, const float* __restrict__ wih,
    const uint32_t* __restrict__ wp, const float* __restrict__ bh,
    __half* __restrict__ hbuf) {
  __shared__ __align__(16) uint32_t h2s[HID / 2];  // h as fp16 pairs
  __shared__ float part[8][HID];                   // 16 KB partials

  const int b   = blockIdx.x;
  const int tid = threadIdx.x;
  const int kq  = tid >> 7;
  const int nb  = tid & 127;
  const int n0  = nb * 4;

  if (tid < HID / 2) h2s[tid] = 0u;  // h0 = 0
  const float bh_r = (tid < HID) ? bh[tid] : 0.f;
  const int xrow = b * S_LEN;
  __syncthreads();

  for (int t = 0; t < S_LEN; ++t) {
    const int tok = x[xrow + t];

    float acc0 = 0.f, acc1 = 0.f, acc2 = 0.f, acc3 = 0.f;
#pragma unroll
    for (int c = 0; c < 8; ++c) {
      // 4 h-pairs at once (broadcast LDS read)
      const uint4 hc = *((const uint4*)&h2s[kq * 32 + c * 4]);
      const uint32_t hv[4] = {hc.x, hc.y, hc.z, hc.w};
#pragma unroll
      for (int j = 0; j < 4; ++j) {
        const int k2 = kq * 32 + c * 4 + j;
        const uint4 w4 = *((const uint4*)&wp[k2 * HID + n0]);  // 4 cols, coalesced
        acc0 = fdot2f(w4.x, hv[j], acc0);
        acc1 = fdot2f(w4.y, hv[j], acc1);
        acc2 = fdot2f(w4.z, hv[j], acc2);
        acc3 = fdot2f(w4.w, hv[j], acc3);
      }
    }
    *((float4*)&part[kq][n0]) = make_float4(acc0, acc1, acc2, acc3);
    __syncthreads();

    if (tid < HID) {
      float s = part[0][tid] + part[1][tid] + part[2][tid] + part[3][tid] +
                part[4][tid] + part[5][tid] + part[6][tid] + part[7][tid];
      s += wih[tok * HID + tid] + bh_r;  // xe gather + b_h
      const float h = tanhf(s);
      const __half hh = __float2half(h);
      hbuf[(size_t)(t * BATCH + b) * HID + tid] = hh;  // store for phase 2
      ((__half*)h2s)[tid] = hh;                         // update recurrent state
    }
    __syncthreads();
  }
}

// ---------------- phase 2: y = h @ W_hy + b_y  (fp16 MFMA, in-place over d_out) ----------------
// 1024 blocks x 256 threads; block handles 64 rows (4 waves x 16 rows) x all 256 cols.
__global__ __launch_bounds__(256, 1) void rnn_phase2(
    void* __restrict__ out_, const _Float16* __restrict__ wt,
    const float* __restrict__ by) {
  const int tid = threadIdx.x;
  const int w = tid >> 6;
  const int l = tid & 63;
  const int la = l & 15;
  const int lb = l >> 4;
  const int rowbase = blockIdx.x * 64 + w * 16;

  const _Float16* hb = (const _Float16*)out_;
  float* out = (float*)out_;

  // Load this wave's entire A panel (its 16 rows x K=512) into registers BEFORE any store.
  h8v a[16];
  const _Float16* arow = hb + (size_t)(rowbase + la) * HID + lb * 8;
#pragma unroll
  for (int kk = 0; kk < 16; ++kk)
    a[kk] = *((const h8v*)(arow + kk * 32));

#pragma unroll 1
  for (int cb = 0; cb < 16; ++cb) {
    f4v acc = {0.f, 0.f, 0.f, 0.f};
    const _Float16* brow = wt + (size_t)(cb * 16 + la) * HID + lb * 8;
#pragma unroll
    for (int kk = 0; kk < 16; ++kk) {
      const h8v bf = *((const h8v*)(brow + kk * 32));
      acc = __builtin_amdgcn_mfma_f32_16x16x32_f16(a[kk], bf, acc, 0, 0, 0);
    }
    const int col = cb * 16 + la;
    const float byv = by[col];
#pragma unroll
    for (int r = 0; r < 4; ++r) {
      const int row = rowbase + lb * 4 + r;  // C/D: col = lane&15, row = (lane>>4)*4 + r
      out[(size_t)row * VOC + col] = acc[r] + byv;
    }
  }
}

// ---------------- launch ----------------
extern "C" void kernel_launch(void* const* d_in, const int* in_sizes, int n_in,
                              void* d_out, int out_size, void* d_ws, size_t ws_size,
                              hipStream_t stream) {
  const int*   x   = (const int*)d_in[0];
  const float* wih = (const float*)d_in[1];
  const float* whh = (const float*)d_in[2];
  const float* bh  = (const float*)d_in[3];
  const float* why = (const float*)d_in[4];
  const float* by  = (const float*)d_in[5];

  uint32_t* wp  = (uint32_t*)d_ws;                          // 512 KB packed fp16 W_hh
  _Float16* wt  = (_Float16*)((char*)d_ws + 512 * 1024);    // 256 KB fp16 W_hy^T

  hipLaunchKernelGGL(prep_whh, dim3(512), dim3(256), 0, stream, whh, wp);
  hipLaunchKernelGGL(prep_why, dim3(512), dim3(256), 0, stream, why, wt);
  hipLaunchKernelGGL(rnn_phase1, dim3(BATCH), dim3(1024), 0, stream,
                     x, wih, wp, bh, (__half*)d_out);
  hipLaunchKernelGGL(rnn_phase2, dim3((S_LEN * BATCH) / 64), dim3(256), 0, stream,
                     d_out, wt, by);
}

// Round 5
// 3274.954 us; speedup vs baseline: 1.1019x; 1.1019x over previous
//
#include <hip/hip_runtime.h>
#include <hip/hip_fp16.h>
#include <stdint.h>

#define S_LEN 1024
#define BATCH 64
#define HID   512
#define VOC   256

typedef _Float16 h2v __attribute__((ext_vector_type(2)));
typedef _Float16 h8v __attribute__((ext_vector_type(8)));
typedef float    f4v __attribute__((ext_vector_type(4)));

__device__ __forceinline__ float fdot2f(uint32_t w, uint32_t h, float c) {
#if __has_builtin(__builtin_amdgcn_fdot2)
  return __builtin_amdgcn_fdot2(__builtin_bit_cast(h2v, w),
                                __builtin_bit_cast(h2v, h), c, false);
#else
  h2v a = __builtin_bit_cast(h2v, w);
  h2v b = __builtin_bit_cast(h2v, h);
  return c + (float)a.x * (float)b.x + (float)a.y * (float)b.y;
#endif
}

// ---------------- prep kernels ----------------
// Wp[k2*HID + n] = fp16 pair (W_hh[2*k2][n], W_hh[2*k2+1][n])
__global__ void prep_whh(const float* __restrict__ whh, uint32_t* __restrict__ wp) {
  int idx = blockIdx.x * blockDim.x + threadIdx.x;   // 131072 = 256*512
  int k2 = idx >> 9;
  int n  = idx & 511;
  float a = whh[(2 * k2) * HID + n];
  float b = whh[(2 * k2 + 1) * HID + n];
  h2v p;
  p.x = (_Float16)a;
  p.y = (_Float16)b;
  wp[idx] = __builtin_bit_cast(uint32_t, p);
}

// W_hyT[v*HID + k] = fp16 W_hy[k][v]   (n-major, k contiguous, for MFMA B frags)
__global__ void prep_why(const float* __restrict__ why, _Float16* __restrict__ wt) {
  int idx = blockIdx.x * blockDim.x + threadIdx.x;   // 131072 = 256*512
  int v = idx >> 9;
  int k = idx & 511;
  wt[idx] = (_Float16)why[k * VOC + v];
}

// ---------------- phase 1: recurrence ----------------
// 64 blocks (one per batch), 1024 threads = 16 waves, 1 block/CU.
// thread = (kq = tid>>7 in [0,8), nb = tid&127): owns cols n0=nb*4..+4,
// k-pairs [kq*32, kq*32+32). W_hh slice register-resident: 128 uint32/thread
// (= 512 KB/CU, the whole packed W_hh in the CU's unified VGPR file).
__global__ __launch_bounds__(1024, 4) void rnn_phase1(
    const int* __restrict__ x, const float* __restrict__ wih,
    const uint32_t* __restrict__ wp, const float* __restrict__ bh,
    __half* __restrict__ hbuf) {
  __shared__ __align__(16) uint32_t h2s[HID / 2];  // h as fp16 pairs (1 KB)
  __shared__ float part[8][HID];                   // 16 KB partials
  __shared__ int xtok[S_LEN];                      // 4 KB token row

  const int b   = blockIdx.x;
  const int tid = threadIdx.x;
  const int kq  = tid >> 7;
  const int nb  = tid & 127;
  const int n0  = nb * 4;

  // ---- one-time: weights -> registers (coalesced: nb contiguous per wave)
  uint4 w[8][4];
#pragma unroll
  for (int c = 0; c < 8; ++c)
#pragma unroll
    for (int j = 0; j < 4; ++j)
      w[c][j] = *((const uint4*)&wp[(kq * 32 + c * 4 + j) * HID + n0]);

  xtok[tid] = x[b * S_LEN + tid];          // whole token row to LDS
  if (tid < HID / 2) h2s[tid] = 0u;        // h0 = 0
  const float bh_r = (tid < HID) ? bh[tid] : 0.f;
  __syncthreads();

  for (int t = 0; t < S_LEN; ++t) {
    const int tok = xtok[t];
    float xe = 0.f;
    if (tid < HID) xe = wih[tok * HID + tid];  // issued early; used after B1

    float acc0 = 0.f, acc1 = 0.f, acc2 = 0.f, acc3 = 0.f;
#pragma unroll
    for (int c = 0; c < 8; ++c) {
      // wave-uniform (broadcast) LDS read of 4 h-pairs
      const uint4 hc = *((const uint4*)&h2s[kq * 32 + c * 4]);
      const uint32_t hv[4] = {hc.x, hc.y, hc.z, hc.w};
#pragma unroll
      for (int j = 0; j < 4; ++j) {
        acc0 = fdot2f(w[c][j].x, hv[j], acc0);
        acc1 = fdot2f(w[c][j].y, hv[j], acc1);
        acc2 = fdot2f(w[c][j].z, hv[j], acc2);
        acc3 = fdot2f(w[c][j].w, hv[j], acc3);
      }
    }
    *((float4*)&part[kq][n0]) = make_float4(acc0, acc1, acc2, acc3);
    __syncthreads();  // B1: partials ready (also: all h reads of step t done)

    if (tid < HID) {
      float s = part[0][tid] + part[1][tid] + part[2][tid] + part[3][tid] +
                part[4][tid] + part[5][tid] + part[6][tid] + part[7][tid];
      s += xe + bh_r;
      // tanh via v_exp_f32: |s| <= ~23, no overflow; rel err ~1e-6
      const float e  = __builtin_amdgcn_exp2f(s * 2.885390081777927f);  // e^(2s)
      const float h  = 1.0f - 2.0f * __builtin_amdgcn_rcpf(e + 1.0f);
      const __half hh = __float2half(h);
      hbuf[(size_t)(t * BATCH + b) * HID + tid] = hh;  // history for phase 2
      ((__half*)h2s)[tid] = hh;                         // recurrent state
    }
    __syncthreads();  // B2: new h visible before next step's reads
  }
}

// ---------------- phase 2: y = h @ W_hy + b_y  (fp16 MFMA, in-place over d_out) ----------------
// 1024 blocks x 256 threads; block handles 64 rows (4 waves x 16 rows) x all 256 cols.
__global__ __launch_bounds__(256, 1) void rnn_phase2(
    void* __restrict__ out_, const _Float16* __restrict__ wt,
    const float* __restrict__ by) {
  const int tid = threadIdx.x;
  const int w = tid >> 6;
  const int l = tid & 63;
  const int la = l & 15;
  const int lb = l >> 4;
  const int rowbase = blockIdx.x * 64 + w * 16;

  const _Float16* hb = (const _Float16*)out_;
  float* out = (float*)out_;

  // Load this wave's entire A panel (its 16 rows x K=512) into registers BEFORE any store.
  h8v a[16];
  const _Float16* arow = hb + (size_t)(rowbase + la) * HID + lb * 8;
#pragma unroll
  for (int kk = 0; kk < 16; ++kk)
    a[kk] = *((const h8v*)(arow + kk * 32));

#pragma unroll 1
  for (int cb = 0; cb < 16; ++cb) {
    f4v acc = {0.f, 0.f, 0.f, 0.f};
    const _Float16* brow = wt + (size_t)(cb * 16 + la) * HID + lb * 8;
#pragma unroll
    for (int kk = 0; kk < 16; ++kk) {
      const h8v bf = *((const h8v*)(brow + kk * 32));
      acc = __builtin_amdgcn_mfma_f32_16x16x32_f16(a[kk], bf, acc, 0, 0, 0);
    }
    const int col = cb * 16 + la;
    const float byv = by[col];
#pragma unroll
    for (int r = 0; r < 4; ++r) {
      const int row = rowbase + lb * 4 + r;  // C/D: col = lane&15, row = (lane>>4)*4 + r
      out[(size_t)row * VOC + col] = acc[r] + byv;
    }
  }
}

// ---------------- launch ----------------
extern "C" void kernel_launch(void* const* d_in, const int* in_sizes, int n_in,
                              void* d_out, int out_size, void* d_ws, size_t ws_size,
                              hipStream_t stream) {
  const int*   x   = (const int*)d_in[0];
  const float* wih = (const float*)d_in[1];
  const float* whh = (const float*)d_in[2];
  const float* bh  = (const float*)d_in[3];
  const float* why = (const float*)d_in[4];
  const float* by  = (const float*)d_in[5];

  uint32_t* wp  = (uint32_t*)d_ws;                          // 512 KB packed fp16 W_hh
  _Float16* wt  = (_Float16*)((char*)d_ws + 512 * 1024);    // 256 KB fp16 W_hy^T

  hipLaunchKernelGGL(prep_whh, dim3(512), dim3(256), 0, stream, whh, wp);
  hipLaunchKernelGGL(prep_why, dim3(512), dim3(256), 0, stream, why, wt);
  hipLaunchKernelGGL(rnn_phase1, dim3(BATCH), dim3(1024), 0, stream,
                     x, wih, wp, bh, (__half*)d_out);
  hipLaunchKernelGGL(rnn_phase2, dim3((S_LEN * BATCH) / 64), dim3(256), 0, stream,
                     d_out, wt, by);
}

// Round 6
// 1734.146 us; speedup vs baseline: 2.0810x; 1.8885x over previous
//
#include <hip/hip_runtime.h>
#include <hip/hip_fp16.h>
#include <stdint.h>

#define S_LEN 1024
#define BATCH 64
#define HID   512
#define VOC   256

typedef _Float16 h2v __attribute__((ext_vector_type(2)));
typedef _Float16 h8v __attribute__((ext_vector_type(8)));
typedef float    f4v __attribute__((ext_vector_type(4)));

__device__ __forceinline__ float fdot2f(uint32_t w, uint32_t h, float c) {
#if __has_builtin(__builtin_amdgcn_fdot2)
  return __builtin_amdgcn_fdot2(__builtin_bit_cast(h2v, w),
                                __builtin_bit_cast(h2v, h), c, false);
#else
  h2v a = __builtin_bit_cast(h2v, w);
  h2v b = __builtin_bit_cast(h2v, h);
  return c + (float)a.x * (float)b.x + (float)a.y * (float)b.y;
#endif
}

// ---------------- prep kernels ----------------
// Wp[k2*HID + n] = fp16 pair (W_hh[2*k2][n], W_hh[2*k2+1][n])
__global__ void prep_whh(const float* __restrict__ whh, uint32_t* __restrict__ wp) {
  int idx = blockIdx.x * blockDim.x + threadIdx.x;   // 131072
  int k2 = idx >> 9;
  int n  = idx & 511;
  float a = whh[(2 * k2) * HID + n];
  float b = whh[(2 * k2 + 1) * HID + n];
  h2v p;
  p.x = (_Float16)a;
  p.y = (_Float16)b;
  wp[idx] = __builtin_bit_cast(uint32_t, p);
}

// W_hyT[v*HID + k] = fp16 W_hy[k][v]
__global__ void prep_why(const float* __restrict__ why, _Float16* __restrict__ wt) {
  int idx = blockIdx.x * blockDim.x + threadIdx.x;   // 131072
  int v = idx >> 9;
  int k = idx & 511;
  wt[idx] = (_Float16)why[k * VOC + v];
}

// ---------------- phase 1: recurrence ----------------
// 64 blocks (one per batch), 1024 threads = 16 waves, 1 block/CU.
// thread (kq=tid>>7, nb=tid&127): cols n0=nb*4..+3, k2-slices s=0..31 at kq*32+s.
// Residency: s=0..19 VGPR (80 regs, 320 KB/CU, asm keep-alive vs remat),
//            s=20..27 LDS (128 KB dynamic), s=28..31 streamed L1/L2 (64 KB/step).
__global__ __launch_bounds__(1024, 4) void rnn_phase1(
    const int* __restrict__ x, const float* __restrict__ wih,
    const uint32_t* __restrict__ wp, const float* __restrict__ bh,
    __half* __restrict__ hbuf) {
  __shared__ __align__(16) uint32_t h2s[HID / 2];  // 1 KB
  __shared__ float part[8][HID];                   // 16 KB
  __shared__ int xtok[S_LEN];                      // 4 KB
  extern __shared__ __align__(16) uint4 lw[];      // 8*1024 uint4 = 128 KB

  const int b   = blockIdx.x;
  const int tid = threadIdx.x;
  const int kq  = tid >> 7;
  const int nb  = tid & 127;
  const int n0  = nb * 4;

  // ---- register-resident slices
  uint4 w[20];
#pragma unroll
  for (int s = 0; s < 20; ++s)
    w[s] = *((const uint4*)&wp[(kq * 32 + s) * HID + n0]);
#pragma unroll
  for (int s = 0; s < 20; ++s)
    asm volatile("" : "+v"(w[s].x), "+v"(w[s].y), "+v"(w[s].z), "+v"(w[s].w));

  // ---- LDS-resident slices (own weights at lw[s][tid], b128 conflict-free)
#pragma unroll
  for (int s = 0; s < 8; ++s)
    lw[s * 1024 + tid] = *((const uint4*)&wp[(kq * 32 + 20 + s) * HID + n0]);

  xtok[tid] = x[b * S_LEN + tid];
  if (tid < HID / 2) h2s[tid] = 0u;
  const float bh_r = (tid < HID) ? bh[tid] : 0.f;
  __syncthreads();

  for (int t = 0; t < S_LEN; ++t) {
    const int tok = xtok[t];
    float xe = 0.f;
    if (tid < HID) xe = wih[tok * HID + tid];  // early issue; used after B1

    // streamed slices: issue loads early (loop-invariant addresses, L1/L2-hot)
    const uint4 g0 = *((const uint4*)&wp[(kq * 32 + 28) * HID + n0]);
    const uint4 g1 = *((const uint4*)&wp[(kq * 32 + 29) * HID + n0]);
    const uint4 g2 = *((const uint4*)&wp[(kq * 32 + 30) * HID + n0]);
    const uint4 g3 = *((const uint4*)&wp[(kq * 32 + 31) * HID + n0]);

    float a0 = 0.f, a1 = 0.f, a2 = 0.f, a3 = 0.f;

    // register slices (s = c*4+j, c = 0..4)
#pragma unroll
    for (int c = 0; c < 5; ++c) {
      const uint4 hc = *((const uint4*)&h2s[kq * 32 + c * 4]);  // broadcast
      a0 = fdot2f(w[c*4+0].x, hc.x, a0); a1 = fdot2f(w[c*4+0].y, hc.x, a1);
      a2 = fdot2f(w[c*4+0].z, hc.x, a2); a3 = fdot2f(w[c*4+0].w, hc.x, a3);
      a0 = fdot2f(w[c*4+1].x, hc.y, a0); a1 = fdot2f(w[c*4+1].y, hc.y, a1);
      a2 = fdot2f(w[c*4+1].z, hc.y, a2); a3 = fdot2f(w[c*4+1].w, hc.y, a3);
      a0 = fdot2f(w[c*4+2].x, hc.z, a0); a1 = fdot2f(w[c*4+2].y, hc.z, a1);
      a2 = fdot2f(w[c*4+2].z, hc.z, a2); a3 = fdot2f(w[c*4+2].w, hc.z, a3);
      a0 = fdot2f(w[c*4+3].x, hc.w, a0); a1 = fdot2f(w[c*4+3].y, hc.w, a1);
      a2 = fdot2f(w[c*4+3].z, hc.w, a2); a3 = fdot2f(w[c*4+3].w, hc.w, a3);
    }

    // LDS slices (c = 0..1 -> s = 20..27)
#pragma unroll
    for (int c = 0; c < 2; ++c) {
      const uint4 hc = *((const uint4*)&h2s[kq * 32 + 20 + c * 4]);
      const uint4 l0 = lw[(c * 4 + 0) * 1024 + tid];
      const uint4 l1 = lw[(c * 4 + 1) * 1024 + tid];
      const uint4 l2 = lw[(c * 4 + 2) * 1024 + tid];
      const uint4 l3 = lw[(c * 4 + 3) * 1024 + tid];
      a0 = fdot2f(l0.x, hc.x, a0); a1 = fdot2f(l0.y, hc.x, a1);
      a2 = fdot2f(l0.z, hc.x, a2); a3 = fdot2f(l0.w, hc.x, a3);
      a0 = fdot2f(l1.x, hc.y, a0); a1 = fdot2f(l1.y, hc.y, a1);
      a2 = fdot2f(l1.z, hc.y, a2); a3 = fdot2f(l1.w, hc.y, a3);
      a0 = fdot2f(l2.x, hc.z, a0); a1 = fdot2f(l2.y, hc.z, a1);
      a2 = fdot2f(l2.z, hc.z, a2); a3 = fdot2f(l2.w, hc.z, a3);
      a0 = fdot2f(l3.x, hc.w, a0); a1 = fdot2f(l3.y, hc.w, a1);
      a2 = fdot2f(l3.z, hc.w, a2); a3 = fdot2f(l3.w, hc.w, a3);
    }

    // streamed slices (s = 28..31)
    {
      const uint4 hc = *((const uint4*)&h2s[kq * 32 + 28]);
      a0 = fdot2f(g0.x, hc.x, a0); a1 = fdot2f(g0.y, hc.x, a1);
      a2 = fdot2f(g0.z, hc.x, a2); a3 = fdot2f(g0.w, hc.x, a3);
      a0 = fdot2f(g1.x, hc.y, a0); a1 = fdot2f(g1.y, hc.y, a1);
      a2 = fdot2f(g1.z, hc.y, a2); a3 = fdot2f(g1.w, hc.y, a3);
      a0 = fdot2f(g2.x, hc.z, a0); a1 = fdot2f(g2.y, hc.z, a1);
      a2 = fdot2f(g2.z, hc.z, a2); a3 = fdot2f(g2.w, hc.z, a3);
      a0 = fdot2f(g3.x, hc.w, a0); a1 = fdot2f(g3.y, hc.w, a1);
      a2 = fdot2f(g3.z, hc.w, a2); a3 = fdot2f(g3.w, hc.w, a3);
    }

    *((float4*)&part[kq][n0]) = make_float4(a0, a1, a2, a3);
    __syncthreads();  // B1

    if (tid < HID) {
      float s = part[0][tid] + part[1][tid] + part[2][tid] + part[3][tid] +
                part[4][tid] + part[5][tid] + part[6][tid] + part[7][tid];
      s += xe + bh_r;
      const float e = __builtin_amdgcn_exp2f(s * 2.885390081777927f);  // e^(2s)
      const float h = 1.0f - 2.0f * __builtin_amdgcn_rcpf(e + 1.0f);
      const __half hh = __float2half(h);
      hbuf[(size_t)(t * BATCH + b) * HID + tid] = hh;
      ((__half*)h2s)[tid] = hh;
    }
    __syncthreads();  // B2
  }
}

// ---------------- phase 2: y = h @ W_hy + b_y (fp16 MFMA, in-place over d_out) ----
__global__ __launch_bounds__(256, 1) void rnn_phase2(
    void* __restrict__ out_, const _Float16* __restrict__ wt,
    const float* __restrict__ by) {
  const int tid = threadIdx.x;
  const int w = tid >> 6;
  const int l = tid & 63;
  const int la = l & 15;
  const int lb = l >> 4;
  const int rowbase = blockIdx.x * 64 + w * 16;

  const _Float16* hb = (const _Float16*)out_;
  float* out = (float*)out_;

  h8v a[16];
  const _Float16* arow = hb + (size_t)(rowbase + la) * HID + lb * 8;
#pragma unroll
  for (int kk = 0; kk < 16; ++kk)
    a[kk] = *((const h8v*)(arow + kk * 32));

#pragma unroll 1
  for (int cb = 0; cb < 16; ++cb) {
    f4v acc = {0.f, 0.f, 0.f, 0.f};
    const _Float16* brow = wt + (size_t)(cb * 16 + la) * HID + lb * 8;
#pragma unroll
    for (int kk = 0; kk < 16; ++kk) {
      const h8v bf = *((const h8v*)(brow + kk * 32));
      acc = __builtin_amdgcn_mfma_f32_16x16x32_f16(a[kk], bf, acc, 0, 0, 0);
    }
    const int col = cb * 16 + la;
    const float byv = by[col];
#pragma unroll
    for (int r = 0; r < 4; ++r) {
      const int row = rowbase + lb * 4 + r;
      out[(size_t)row * VOC + col] = acc[r] + byv;
    }
  }
}

// ---------------- launch ----------------
extern "C" void kernel_launch(void* const* d_in, const int* in_sizes, int n_in,
                              void* d_out, int out_size, void* d_ws, size_t ws_size,
                              hipStream_t stream) {
  const int*   x   = (const int*)d_in[0];
  const float* wih = (const float*)d_in[1];
  const float* whh = (const float*)d_in[2];
  const float* bh  = (const float*)d_in[3];
  const float* why = (const float*)d_in[4];
  const float* by  = (const float*)d_in[5];

  uint32_t* wp  = (uint32_t*)d_ws;                          // 512 KB packed fp16 W_hh
  _Float16* wt  = (_Float16*)((char*)d_ws + 512 * 1024);    // 256 KB fp16 W_hy^T

  hipLaunchKernelGGL(prep_whh, dim3(512), dim3(256), 0, stream, whh, wp);
  hipLaunchKernelGGL(prep_why, dim3(512), dim3(256), 0, stream, why, wt);
  hipLaunchKernelGGL(rnn_phase1, dim3(BATCH), dim3(1024), 131072, stream,
                     x, wih, wp, bh, (__half*)d_out);
  hipLaunchKernelGGL(rnn_phase2, dim3((S_LEN * BATCH) / 64), dim3(256), 0, stream,
                     d_out, wt, by);
}